// Round 4
// baseline (1593.401 us; speedup 1.0000x reference)
//
#include <hip/hip_runtime.h>

#define NN 8192      // nodes
#define SS 20        // seq len
#define DD 256       // feat dim = H
#define RGATE 1024   // 4H
#define KKD 512      // D + H

typedef __attribute__((ext_vector_type(8))) short short8;
typedef __attribute__((ext_vector_type(4))) float f32x4;

__device__ __forceinline__ unsigned short f2bf(float f) {
    unsigned int u = __float_as_uint(f);
    u += 0x7FFFu + ((u >> 16) & 1u);   // round-to-nearest-even
    return (unsigned short)(u >> 16);
}

__device__ __forceinline__ void async_copy16(const void* g, void* l) {
    __builtin_amdgcn_global_load_lds(
        (const __attribute__((address_space(1))) void*)g,
        (__attribute__((address_space(3))) void*)l, 16, 0, 0);
}

__device__ __forceinline__ float sigm(float x) { return 1.0f / (1.0f + __expf(-x)); }
__device__ __forceinline__ float tanh_(float x) { return 2.0f / (1.0f + __expf(-2.0f * x)) - 1.0f; }

// ---------------------------------------------------------------------------
// Weight repack: Wcat[dir][r'][k], r' = 4*j + gate; k<256 -> w_ih, else w_hh.
// ---------------------------------------------------------------------------
__global__ void convert_w(const float* __restrict__ wihf, const float* __restrict__ whhf,
                          const float* __restrict__ bf,   const float* __restrict__ wihb,
                          const float* __restrict__ whhb, const float* __restrict__ bb,
                          unsigned short* __restrict__ Wcat, float* __restrict__ bperm) {
    const int idx = blockIdx.x * 256 + threadIdx.x;   // < 2*1024*512
    const int dir = idx >> 19;
    const int rem = idx & ((1 << 19) - 1);
    const int rp  = rem >> 9;          // r' in [0,1024)
    const int k   = rem & 511;
    const int j   = rp >> 2, gi = rp & 3;
    const int r   = gi * 256 + j;      // original row (PyTorch i,f,g,o blocks)
    const float* wih = dir ? wihb : wihf;
    const float* whh = dir ? whhb : whhf;
    const float v = (k < 256) ? wih[r * 256 + k] : whh[r * 256 + (k - 256)];
    Wcat[idx] = f2bf(v);
    if (k == 0) {
        const float* b = dir ? bb : bf;
        bperm[dir * 1024 + rp] = b[r];
    }
}

// ---------------------------------------------------------------------------
// Gather neighbor embeddings to bf16: X[t][n][256]. 4 waves/block, 1 row/wave.
// ---------------------------------------------------------------------------
__global__ __launch_bounds__(256) void gather_x(const float* __restrict__ emb,
                                                const int* __restrict__ idx,
                                                unsigned short* __restrict__ X) {
    const int w = threadIdx.x >> 6, lane = threadIdx.x & 63;
    #pragma unroll 4
    for (int i = 0; i < 16; ++i) {
        const int rid = (blockIdx.x * 16 + i) * 4 + w;   // 0..163839 = n*SS+t
        const int n = rid / SS, t = rid - n * SS;
        const int row = idx[rid];
        const float4 v = ((const float4*)(emb + (size_t)row * DD))[lane];
        ushort4 o;
        o.x = f2bf(v.x); o.y = f2bf(v.y); o.z = f2bf(v.z); o.w = f2bf(v.w);
        ((ushort4*)(X + ((size_t)t * NN + n) * DD))[lane] = o;
    }
}

// ---------------------------------------------------------------------------
// Persistent bidirectional LSTM. 256 blocks (1/CU), 256 threads (4 waves).
// Block = (dir, 64-node slab): owns all 1024 gate cols for its rows, so h
// never leaves the block (LDS) and c never leaves registers. No grid sync.
//   dir  = blockIdx&1 (XCD parity), mslab = ((b&7)>>1)*32 + (b>>3).
// Per step: each wave w computes gate cols w*256..+255 as 4 chunks of 64
// (acc[4][4], 16x16x32 MFMA), A-frags from LDS (Ax ping-pong + Ah), B-frags
// DIRECT global->VGPR from XCD-L2-resident W with 1-kt prefetch pipeline.
// x_{t+1} staged via global_load_lds into the other Ax buffer at step start
// (latency hidden under the whole step). 2 intra-block barriers/step.
// LDS layout: rows of 512B (32 x 16B segs), seg XOR-swizzled by (row&7) so
// frag ds_read_b128 and staging both run conflict-free (verified R3: 0 cnt).
// ---------------------------------------------------------------------------
__global__ __launch_bounds__(256, 1) void lstm_persist(
    const unsigned short* __restrict__ X,      // [SS][NN][256] bf16
    const unsigned short* __restrict__ Wcat,   // [2][1024][512] bf16
    const float* __restrict__ bperm,           // [2][1024]
    float* __restrict__ hsum) {                // [NN] f32
    const int b    = blockIdx.x;
    const int xcd  = b & 7;
    const int dir  = xcd & 1;
    const int mslab = ((xcd >> 1) << 5) + (b >> 3);   // 0..127
    const int m0   = mslab * 64;

    const unsigned short* W  = Wcat + (size_t)dir * RGATE * KKD;
    const float*          bp = bperm + dir * RGATE;

    __shared__ __align__(16) unsigned short Axb[2][64 * 256];  // 2 x 32 KB x_t ping-pong
    __shared__ __align__(16) unsigned short Ah[64 * 256];      // 32 KB h state
    __shared__ __align__(16) float escr[4][16 * 68];           // 17408 B epilogue scratch

    const int tid  = threadIdx.x;
    const int lane = tid & 63;
    const int w    = tid >> 6;
    const int quad = lane >> 4;
    const int jq   = lane & 3;

    // zero Ah (h_0 = 0)
    {
        float4 z = {0.f, 0.f, 0.f, 0.f};
        float4* p = (float4*)Ah;
        #pragma unroll
        for (int i = 0; i < 8; ++i) p[tid * 8 + i] = z;
    }

    // stage x_t into Axb[buf]: per wave 16 rows, 8 issues of 2 rows (1024 B)
    const int r2  = lane >> 5;         // which row of the pair
    const int seg = lane & 31;
    auto stage_x = [&](int t, int buf) {
        const unsigned short* Xt = X + ((size_t)t * NN + m0) * DD;
        unsigned short* dst = Axb[buf];
        #pragma unroll
        for (int i = 0; i < 8; ++i) {
            const int row = w * 16 + i * 2 + r2;
            const int gs  = seg ^ (row & 7);
            async_copy16(Xt + (size_t)row * DD + gs * 8,
                         (void*)((char*)dst + (w * 16 + i * 2) * 512));
        }
    };

    // bias preload: bias[nb][jj] = gates (f32x4) of hidden unit j
    f32x4 bias[4][4];
    #pragma unroll
    for (int nb = 0; nb < 4; ++nb)
        #pragma unroll
        for (int jj = 0; jj < 4; ++jj) {
            const int j = w * 64 + nb * 16 + jq * 4 + jj;
            bias[nb][jj] = *(const f32x4*)(bp + 4 * j);
        }

    f32x4 cst[4][4];                   // c state [nb][mt]
    #pragma unroll
    for (int nb = 0; nb < 4; ++nb)
        #pragma unroll
        for (int mt = 0; mt < 4; ++mt) cst[nb][mt] = f32x4{0.f, 0.f, 0.f, 0.f};
    float hs[4] = {0.f, 0.f, 0.f, 0.f};   // per-row running h sums [mt]
    ushort4 hreg[4][4];                   // packed h for LDS writeback [nb][mt]

    const int tstep = dir ? -1 : 1;
    int t = dir ? (SS - 1) : 0;
    stage_x(t, 0);
    __syncthreads();                   // drains stage (vmcnt0) + Ah zeros

    // per-lane W byte offset: row part (w*256 + lane&15)*1024 + quad k-slice
    const char* Wp = (const char*)W + (size_t)(w * 256 + (lane & 15)) * 1024 + quad * 16;

    for (int s = 0; s < SS; ++s, t += tstep) {
        const unsigned short* Axc = Axb[s & 1];
        if (s + 1 < SS) stage_x(t + tstep, (s + 1) & 1);   // hide under this step

        #pragma unroll
        for (int nb = 0; nb < 4; ++nb) {
            const char* Wnb = Wp + nb * 65536;
            f32x4 acc[4][4];
            #pragma unroll
            for (int i = 0; i < 4; ++i)
                #pragma unroll
                for (int j = 0; j < 4; ++j) acc[i][j] = f32x4{0.f, 0.f, 0.f, 0.f};

            short8 Bb[2][2][4];
            #pragma unroll
            for (int kk = 0; kk < 2; ++kk)
                #pragma unroll
                for (int nt = 0; nt < 4; ++nt)
                    Bb[0][kk][nt] = *(const short8*)(Wnb + nt * 16384 + kk * 64);

            #pragma unroll
            for (int kt = 0; kt < 8; ++kt) {
                const int cur = kt & 1, nxt = cur ^ 1;
                if (kt < 7) {
                    #pragma unroll
                    for (int kk = 0; kk < 2; ++kk)
                        #pragma unroll
                        for (int nt = 0; nt < 4; ++nt)
                            Bb[nxt][kk][nt] = *(const short8*)(Wnb + nt * 16384 + (kt + 1) * 128 + kk * 64);
                }
                const unsigned short* Abase = (kt < 4) ? Axc : Ah;
                #pragma unroll
                for (int kk = 0; kk < 2; ++kk) {
                    short8 af[4];
                    const int segb = (kt & 3) * 8 + kk * 4 + quad;   // global seg 0..31
                    #pragma unroll
                    for (int mt = 0; mt < 4; ++mt) {
                        const int r = mt * 16 + (lane & 15);         // r&7 == lane&7
                        af[mt] = *(const short8*)((const char*)Abase + r * 512
                                                  + ((segb ^ (lane & 7)) << 4));
                    }
                    #pragma unroll
                    for (int mt = 0; mt < 4; ++mt)
                        #pragma unroll
                        for (int nt = 0; nt < 4; ++nt)
                            acc[mt][nt] = __builtin_amdgcn_mfma_f32_16x16x32_bf16(
                                af[mt], Bb[cur][kk][nt], acc[mt][nt], 0, 0, 0);
                }
            }

            // epilogue: regroup gates via wave-private LDS scratch, update c/h
            float* my = escr[w];
            #pragma unroll
            for (int mt = 0; mt < 4; ++mt) {
                #pragma unroll
                for (int nt = 0; nt < 4; ++nt)
                    #pragma unroll
                    for (int v = 0; v < 4; ++v)
                        my[(quad * 4 + v) * 68 + nt * 16 + (lane & 15)] = acc[mt][nt][v];
                asm volatile("s_waitcnt lgkmcnt(0)" ::: "memory");
                const int rl = lane >> 2;            // row within 16-slab
                f32x4 cold = cst[nb][mt], cnew;
                ushort4 hp;
                float lsum = 0.f;
                #pragma unroll
                for (int jj = 0; jj < 4; ++jj) {
                    f32x4 g  = *(const f32x4*)(my + rl * 68 + (jq * 4 + jj) * 4);
                    f32x4 bb = bias[nb][jj];
                    const float gi = sigm(g.x + bb.x);
                    const float gf = sigm(g.y + bb.y);
                    const float gg = tanh_(g.z + bb.z);
                    const float go = sigm(g.w + bb.w);
                    const float cn = gf * cold[jj] + gi * gg;
                    cnew[jj] = cn;
                    const float hv = go * tanh_(cn);
                    lsum += hv;
                    ((unsigned short*)&hp)[jj] = f2bf(hv);
                }
                cst[nb][mt] = cnew;
                hs[mt] += lsum;
                hreg[nb][mt] = hp;
            }
        }

        __syncthreads();   // all waves done reading Ah/Axc; x-stage drained

        // write h(s+1) into Ah (A-frag layout, swizzled); 8B per (nb,mt)
        #pragma unroll
        for (int nb = 0; nb < 4; ++nb)
            #pragma unroll
            for (int mt = 0; mt < 4; ++mt) {
                const int row = mt * 16 + (lane >> 2);
                const int j   = w * 64 + nb * 16 + jq * 4;   // hidden col
                char* dst = (char*)Ah + row * 512
                            + (((j >> 3) ^ (row & 7)) << 4) + ((j & 4) << 1);
                *(ushort4*)dst = hreg[nb][mt];
            }
        __syncthreads();   // h visible to all waves
    }

    // final: reduce hs over the 4 gate-lanes, one atomic per (wave,row)
    #pragma unroll
    for (int mt = 0; mt < 4; ++mt) {
        float v = hs[mt];
        v += __shfl_xor(v, 1);
        v += __shfl_xor(v, 2);
        if (jq == 0) atomicAdd(&hsum[m0 + mt * 16 + (lane >> 2)], v);
    }
}

__global__ void bcast_out(const float* __restrict__ hsum, float* __restrict__ out) {
    const int n = blockIdx.x;
    const float v = hsum[n] * (1.0f / 512.0f);
    float2 p; p.x = v; p.y = v;
    ((float2*)(out + (size_t)n * 512))[threadIdx.x] = p;
}

extern "C" void kernel_launch(void* const* d_in, const int* in_sizes, int n_in,
                              void* d_out, int out_size, void* d_ws, size_t ws_size,
                              hipStream_t stream) {
    const float* emb  = (const float*)d_in[0];
    const float* wihf = (const float*)d_in[1];
    const float* whhf = (const float*)d_in[2];
    const float* bf   = (const float*)d_in[3];
    const float* wihb = (const float*)d_in[4];
    const float* whhb = (const float*)d_in[5];
    const float* bb   = (const float*)d_in[6];
    const int*   idx  = (const int*)d_in[7];
    float* out = (float*)d_out;

    // workspace layout (bytes)
    char* ws = (char*)d_ws;
    unsigned short* X     = (unsigned short*)(ws);               // 83,886,080  X[t][n][256] bf16
    unsigned short* Wcat  = (unsigned short*)(ws + 83886080);    //  2,097,152  [2][1024][512] bf16
    float*          bperm = (float*)(ws + 85983232);             //      8,192  [2][1024] f32
    float*          hsum  = (float*)(ws + 85991424);             //     32,768  [8192] f32
    // total: 86,024,192 B

    hipMemsetAsync(hsum, 0, 32768, stream);

    convert_w<<<4096, 256, 0, stream>>>(wihf, whhf, bf, wihb, whhb, bb, Wcat, bperm);
    gather_x<<<2560, 256, 0, stream>>>(emb, idx, X);
    lstm_persist<<<256, 256, 0, stream>>>(X, Wcat, bperm, hsum);
    bcast_out<<<NN, 256, 0, stream>>>(hsum, out);
}

// Round 5
// 1354.898 us; speedup vs baseline: 1.1760x; 1.1760x over previous
//
#include <hip/hip_runtime.h>

#define NN 8192      // nodes
#define SS 20        // seq len
#define DD 256       // feat dim = H
#define RGATE 1024   // 4H
#define KKD 512      // D + H

typedef __attribute__((ext_vector_type(8))) short short8;
typedef __attribute__((ext_vector_type(4))) float f32x4;

__device__ __forceinline__ unsigned short f2bf(float f) {
    unsigned int u = __float_as_uint(f);
    u += 0x7FFFu + ((u >> 16) & 1u);   // round-to-nearest-even
    return (unsigned short)(u >> 16);
}

__device__ __forceinline__ void async_copy16(const void* g, void* l) {
    __builtin_amdgcn_global_load_lds(
        (const __attribute__((address_space(1))) void*)g,
        (__attribute__((address_space(3))) void*)l, 16, 0, 0);
}

__device__ __forceinline__ float sigm(float x) { return 1.0f / (1.0f + __expf(-x)); }
__device__ __forceinline__ float tanh_(float x) { return 2.0f / (1.0f + __expf(-2.0f * x)) - 1.0f; }

// ---------------------------------------------------------------------------
// Weight repack: Wcat[dir][r'][k], r' = 4*j + gate; k<256 -> w_ih, else w_hh.
// ---------------------------------------------------------------------------
__global__ void convert_w(const float* __restrict__ wihf, const float* __restrict__ whhf,
                          const float* __restrict__ bf,   const float* __restrict__ wihb,
                          const float* __restrict__ whhb, const float* __restrict__ bb,
                          unsigned short* __restrict__ Wcat, float* __restrict__ bperm) {
    const int idx = blockIdx.x * 256 + threadIdx.x;   // < 2*1024*512
    const int dir = idx >> 19;
    const int rem = idx & ((1 << 19) - 1);
    const int rp  = rem >> 9;          // r' in [0,1024)
    const int k   = rem & 511;
    const int j   = rp >> 2, gi = rp & 3;
    const int r   = gi * 256 + j;      // original row (PyTorch i,f,g,o blocks)
    const float* wih = dir ? wihb : wihf;
    const float* whh = dir ? whhb : whhf;
    const float v = (k < 256) ? wih[r * 256 + k] : whh[r * 256 + (k - 256)];
    Wcat[idx] = f2bf(v);
    if (k == 0) {
        const float* b = dir ? bb : bf;
        bperm[dir * 1024 + rp] = b[r];
    }
}

// ---------------------------------------------------------------------------
// Gather neighbor embeddings to bf16: X[t][n][256]. 4 waves/block, 1 row/wave.
// ---------------------------------------------------------------------------
__global__ __launch_bounds__(256) void gather_x(const float* __restrict__ emb,
                                                const int* __restrict__ idx,
                                                unsigned short* __restrict__ X) {
    const int w = threadIdx.x >> 6, lane = threadIdx.x & 63;
    #pragma unroll 4
    for (int i = 0; i < 16; ++i) {
        const int rid = (blockIdx.x * 16 + i) * 4 + w;   // 0..163839 = n*SS+t
        const int n = rid / SS, t = rid - n * SS;
        const int row = idx[rid];
        const float4 v = ((const float4*)(emb + (size_t)row * DD))[lane];
        ushort4 o;
        o.x = f2bf(v.x); o.y = f2bf(v.y); o.z = f2bf(v.z); o.w = f2bf(v.w);
        ((ushort4*)(X + ((size_t)t * NN + n) * DD))[lane] = o;
    }
}

// ---------------------------------------------------------------------------
// Persistent bidirectional LSTM, v2. 256 blocks (1/CU) x 512 threads (8 waves
// -> 2 waves/SIMD for latency hiding; R4's 1 wave/SIMD was a stall disaster).
// Block = (dir, 64-node slab), owns all 1024 gate cols: h stays in LDS, c in
// registers, no inter-block communication, zero grid syncs.
// Wave w owns gate cols [w*128, w*128+128) = hidden units [w*32, w*32+32),
// processed as 2 chunks (nb) of 64 cols: acc[4][4] per chunk.
// Per-thread regs ~210 (R4 needed ~320 and spilled): acc 64 + Bb 64 (1-kt
// prefetch) + cst 32 + af 16 + hreg 16; bias moved to LDS.
// B-frags load DIRECT global->VGPR from XCD-L2-resident W (1 MB/dir).
// x_{t+1} staged via global_load_lds into the other Ax buffer during step s.
// LDS rows of 512B = 32 16B segs, XOR-swizzled by (row&7): conflict-free
// staging + frag reads (R3-verified). 2 barriers/step.
// ---------------------------------------------------------------------------
__global__ __launch_bounds__(512, 1) void lstm_persist(
    const unsigned short* __restrict__ X,      // [SS][NN][256] bf16
    const unsigned short* __restrict__ Wcat,   // [2][1024][512] bf16
    const float* __restrict__ bperm,           // [2][1024]
    float* __restrict__ hsum) {                // [NN] f32
    const int b    = blockIdx.x;
    const int xcd  = b & 7;
    const int dir  = xcd & 1;
    const int mslab = ((xcd >> 1) << 5) + (b >> 3);   // 0..127
    const int m0   = mslab * 64;

    const unsigned short* W  = Wcat + (size_t)dir * RGATE * KKD;
    const float*          bp = bperm + dir * RGATE;

    __shared__ __align__(16) unsigned short Axb[2][64 * 256];  // 2 x 32 KB x_t ping-pong
    __shared__ __align__(16) unsigned short Ah[64 * 256];      // 32 KB h state
    __shared__ __align__(16) float escr[8][16 * 68];           // 34816 B epilogue scratch
    __shared__ __align__(16) float biasl[1024];                // 4 KB bias (dir half)

    const int tid  = threadIdx.x;
    const int lane = tid & 63;
    const int w    = tid >> 6;        // wave 0..7
    const int quad = lane >> 4;
    const int jq   = lane & 3;
    const int l15  = lane & 15;
    const int rl   = lane >> 2;       // 0..15

    // zero Ah (h_0 = 0): 64 B/thread
    {
        float4 z = {0.f, 0.f, 0.f, 0.f};
        float4* p = (float4*)Ah;
        #pragma unroll
        for (int i = 0; i < 4; ++i) p[tid * 4 + i] = z;
    }
    // bias into LDS
    biasl[tid] = bp[tid];
    biasl[tid + 512] = bp[tid + 512];

    // stage x_t into Axb[buf]: per wave 8 rows = 4 issues of 2 rows (1024 B)
    const int r2  = lane >> 5;         // which row of the pair
    const int seg = lane & 31;
    auto stage_x = [&](int t, int buf) {
        const unsigned short* Xt = X + ((size_t)t * NN + m0) * DD;
        unsigned short* dst = Axb[buf];
        #pragma unroll
        for (int i = 0; i < 4; ++i) {
            const int row = w * 8 + i * 2 + r2;
            const int gs  = seg ^ (row & 7);
            async_copy16(Xt + (size_t)row * DD + gs * 8,
                         (void*)((char*)dst + (w * 8 + i * 2) * 512));
        }
    };

    f32x4 cst[2][4];                   // c state [nb][mt]
    #pragma unroll
    for (int nb = 0; nb < 2; ++nb)
        #pragma unroll
        for (int mt = 0; mt < 4; ++mt) cst[nb][mt] = f32x4{0.f, 0.f, 0.f, 0.f};
    float hs[4] = {0.f, 0.f, 0.f, 0.f};   // per-row running h sums [mt]
    ushort4 hreg[2][4];                   // packed h for LDS writeback [nb][mt]

    const int tstep = dir ? -1 : 1;
    int t = dir ? (SS - 1) : 0;
    stage_x(t, 0);
    __syncthreads();                   // drains stage (vmcnt0) + Ah zeros + bias

    // per-lane W byte base: gate-col row (w*128 + l15), quad k-slice
    const char* Wp = (const char*)W + (size_t)(w * 128 + l15) * 1024 + quad * 16;

    for (int s = 0; s < SS; ++s, t += tstep) {
        const unsigned short* Axc = Axb[s & 1];
        if (s + 1 < SS) stage_x(t + tstep, (s + 1) & 1);   // hide under this step

        #pragma unroll
        for (int nb = 0; nb < 2; ++nb) {
            const char* Wnb = Wp + nb * 65536;
            f32x4 acc[4][4];
            #pragma unroll
            for (int i = 0; i < 4; ++i)
                #pragma unroll
                for (int j = 0; j < 4; ++j) acc[i][j] = f32x4{0.f, 0.f, 0.f, 0.f};

            short8 Bb[2][2][4];
            #pragma unroll
            for (int kk = 0; kk < 2; ++kk)
                #pragma unroll
                for (int nt = 0; nt < 4; ++nt)
                    Bb[0][kk][nt] = *(const short8*)(Wnb + nt * 16384 + kk * 64);

            #pragma unroll
            for (int kt = 0; kt < 8; ++kt) {
                const int cur = kt & 1, nxt = cur ^ 1;
                if (kt < 7) {
                    #pragma unroll
                    for (int kk = 0; kk < 2; ++kk)
                        #pragma unroll
                        for (int nt = 0; nt < 4; ++nt)
                            Bb[nxt][kk][nt] = *(const short8*)(Wnb + nt * 16384 + (kt + 1) * 128 + kk * 64);
                }
                const unsigned short* Abase = (kt < 4) ? Axc : Ah;
                #pragma unroll
                for (int kk = 0; kk < 2; ++kk) {
                    short8 af[4];
                    const int segb = (kt & 3) * 8 + kk * 4 + quad;   // global seg 0..31
                    #pragma unroll
                    for (int mt = 0; mt < 4; ++mt) {
                        const int r = mt * 16 + l15;                 // r&7 == lane&7
                        af[mt] = *(const short8*)((const char*)Abase + r * 512
                                                  + ((segb ^ (lane & 7)) << 4));
                    }
                    #pragma unroll
                    for (int mt = 0; mt < 4; ++mt)
                        #pragma unroll
                        for (int nt = 0; nt < 4; ++nt)
                            acc[mt][nt] = __builtin_amdgcn_mfma_f32_16x16x32_bf16(
                                af[mt], Bb[cur][kk][nt], acc[mt][nt], 0, 0, 0);
                }
            }

            // bias for this nb chunk (hoisted over mt): hidden j = w*32+nb*16+jq*4+jj
            f32x4 bias[4];
            #pragma unroll
            for (int jj = 0; jj < 4; ++jj)
                bias[jj] = *(const f32x4*)(biasl + 4 * (w * 32 + nb * 16 + jq * 4 + jj));

            // epilogue: regroup gates via wave-private LDS scratch, update c/h
            float* my = escr[w];
            #pragma unroll
            for (int mt = 0; mt < 4; ++mt) {
                #pragma unroll
                for (int nt = 0; nt < 4; ++nt)
                    #pragma unroll
                    for (int v = 0; v < 4; ++v)
                        my[(quad * 4 + v) * 68 + nt * 16 + l15] = acc[mt][nt][v];
                asm volatile("s_waitcnt lgkmcnt(0)" ::: "memory");
                f32x4 cold = cst[nb][mt], cnew;
                ushort4 hp;
                float lsum = 0.f;
                #pragma unroll
                for (int jj = 0; jj < 4; ++jj) {
                    f32x4 g  = *(const f32x4*)(my + rl * 68 + (jq * 4 + jj) * 4);
                    f32x4 bb = bias[jj];
                    const float gi = sigm(g.x + bb.x);
                    const float gf = sigm(g.y + bb.y);
                    const float gg = tanh_(g.z + bb.z);
                    const float go = sigm(g.w + bb.w);
                    const float cn = gf * cold[jj] + gi * gg;
                    cnew[jj] = cn;
                    const float hv = go * tanh_(cn);
                    lsum += hv;
                    ((unsigned short*)&hp)[jj] = f2bf(hv);
                }
                cst[nb][mt] = cnew;
                hs[mt] += lsum;
                hreg[nb][mt] = hp;
            }
        }

        __syncthreads();   // all waves done reading Ah/Axc; x-stage drained

        // write h(s+1) into Ah (A-frag layout, swizzled); 8B per (nb,mt)
        #pragma unroll
        for (int nb = 0; nb < 2; ++nb)
            #pragma unroll
            for (int mt = 0; mt < 4; ++mt) {
                const int row = mt * 16 + rl;
                const int j   = w * 32 + nb * 16 + jq * 4;   // hidden col
                char* dst = (char*)Ah + row * 512
                            + (((j >> 3) ^ (row & 7)) << 4) + ((j & 4) << 1);
                *(ushort4*)dst = hreg[nb][mt];
            }
        __syncthreads();   // h visible to all waves
    }

    // final: reduce hs over the 4 gate-lanes, one atomic per (wave,row)
    #pragma unroll
    for (int mt = 0; mt < 4; ++mt) {
        float v = hs[mt];
        v += __shfl_xor(v, 1);
        v += __shfl_xor(v, 2);
        if (jq == 0) atomicAdd(&hsum[m0 + mt * 16 + rl], v);
    }
}

__global__ void bcast_out(const float* __restrict__ hsum, float* __restrict__ out) {
    const int n = blockIdx.x;
    const float v = hsum[n] * (1.0f / 512.0f);
    float2 p; p.x = v; p.y = v;
    ((float2*)(out + (size_t)n * 512))[threadIdx.x] = p;
}

extern "C" void kernel_launch(void* const* d_in, const int* in_sizes, int n_in,
                              void* d_out, int out_size, void* d_ws, size_t ws_size,
                              hipStream_t stream) {
    const float* emb  = (const float*)d_in[0];
    const float* wihf = (const float*)d_in[1];
    const float* whhf = (const float*)d_in[2];
    const float* bf   = (const float*)d_in[3];
    const float* wihb = (const float*)d_in[4];
    const float* whhb = (const float*)d_in[5];
    const float* bb   = (const float*)d_in[6];
    const int*   idx  = (const int*)d_in[7];
    float* out = (float*)d_out;

    // workspace layout (bytes)
    char* ws = (char*)d_ws;
    unsigned short* X     = (unsigned short*)(ws);               // 83,886,080  X[t][n][256] bf16
    unsigned short* Wcat  = (unsigned short*)(ws + 83886080);    //  2,097,152  [2][1024][512] bf16
    float*          bperm = (float*)(ws + 85983232);             //      8,192  [2][1024] f32
    float*          hsum  = (float*)(ws + 85991424);             //     32,768  [8192] f32
    // total: 86,024,192 B

    hipMemsetAsync(hsum, 0, 32768, stream);

    convert_w<<<4096, 256, 0, stream>>>(wihf, whhf, bf, wihb, whhb, bb, Wcat, bperm);
    gather_x<<<2560, 256, 0, stream>>>(emb, idx, X);
    lstm_persist<<<256, 512, 0, stream>>>(X, Wcat, bperm, hsum);
    bcast_out<<<NN, 256, 0, stream>>>(hsum, out);
}

// Round 6
// 844.507 us; speedup vs baseline: 1.8868x; 1.6044x over previous
//
#include <hip/hip_runtime.h>

#define NN 8192      // nodes
#define SS 20        // seq len
#define DD 256       // feat dim = H
#define RGATE 1024   // 4H
#define KKD 512      // D + H

typedef __attribute__((ext_vector_type(8))) short short8;
typedef __attribute__((ext_vector_type(4))) float f32x4;

__device__ __forceinline__ unsigned short f2bf(float f) {
    unsigned int u = __float_as_uint(f);
    u += 0x7FFFu + ((u >> 16) & 1u);   // round-to-nearest-even
    return (unsigned short)(u >> 16);
}

__device__ __forceinline__ void async_copy16(const void* g, void* l) {
    __builtin_amdgcn_global_load_lds(
        (const __attribute__((address_space(1))) void*)g,
        (__attribute__((address_space(3))) void*)l, 16, 0, 0);
}

__device__ __forceinline__ float sigm(float x) { return 1.0f / (1.0f + __expf(-x)); }
__device__ __forceinline__ float tanh_(float x) { return 2.0f / (1.0f + __expf(-2.0f * x)) - 1.0f; }

// ---------------------------------------------------------------------------
// Weight repack: Wcat[dir][r'][k], r' = 4*j + gate; k<256 -> w_ih, else w_hh.
// ---------------------------------------------------------------------------
__global__ void convert_w(const float* __restrict__ wihf, const float* __restrict__ whhf,
                          const float* __restrict__ bf,   const float* __restrict__ wihb,
                          const float* __restrict__ whhb, const float* __restrict__ bb,
                          unsigned short* __restrict__ Wcat, float* __restrict__ bperm) {
    const int idx = blockIdx.x * 256 + threadIdx.x;   // < 2*1024*512
    const int dir = idx >> 19;
    const int rem = idx & ((1 << 19) - 1);
    const int rp  = rem >> 9;          // r' in [0,1024)
    const int k   = rem & 511;
    const int j   = rp >> 2, gi = rp & 3;
    const int r   = gi * 256 + j;      // original row (PyTorch i,f,g,o blocks)
    const float* wih = dir ? wihb : wihf;
    const float* whh = dir ? whhb : whhf;
    const float v = (k < 256) ? wih[r * 256 + k] : whh[r * 256 + (k - 256)];
    Wcat[idx] = f2bf(v);
    if (k == 0) {
        const float* b = dir ? bb : bf;
        bperm[dir * 1024 + rp] = b[r];
    }
}

// ---------------------------------------------------------------------------
// Gather neighbor embeddings to bf16: X[t][n][256]. 4 waves/block, 1 row/wave.
// ---------------------------------------------------------------------------
__global__ __launch_bounds__(256) void gather_x(const float* __restrict__ emb,
                                                const int* __restrict__ idx,
                                                unsigned short* __restrict__ X) {
    const int w = threadIdx.x >> 6, lane = threadIdx.x & 63;
    #pragma unroll 4
    for (int i = 0; i < 16; ++i) {
        const int rid = (blockIdx.x * 16 + i) * 4 + w;   // 0..163839 = n*SS+t
        const int n = rid / SS, t = rid - n * SS;
        const int row = idx[rid];
        const float4 v = ((const float4*)(emb + (size_t)row * DD))[lane];
        ushort4 o;
        o.x = f2bf(v.x); o.y = f2bf(v.y); o.z = f2bf(v.z); o.w = f2bf(v.w);
        ((ushort4*)(X + ((size_t)t * NN + n) * DD))[lane] = o;
    }
}

// ---------------------------------------------------------------------------
// One LSTM step, both dirs. Grid 256 (1 block/CU, fully co-resident), 512 thr
// (8 waves). Block tile 256 rows x 256 gate cols; wave tile 64x128:
// acc[4][8] = 128 AGPRs (a-side cap exactly), v-side ~100 (af16+bf32+addr).
// [Allocator rule learned R2/R4/R5: v-side budget = wave-budget/2; overflow
//  spills to scratch -> WRITE_SIZE balloons. Keep W in LDS, not registers.]
// BK=32, 16 rounds, 2-deep LDS double-buffer: stage r+1 issued BEFORE
// compute r, so the load latency R3 exposed serially is hidden under MFMA.
// LDS 64-B rows (4x16B segs), seg' = quad ^ ((row>>1)&3): per-16-lane beat
// each b128 hits 8 window-starts x 2 lanes = 2-way = free.
// h/c in global, XCD-L2-resident via decode: xcd=b&7, dir=b&1 (W per parity),
// mslab tied to XCD-pair so A panels shared by the 4 nblk blocks on-XCD.
// ---------------------------------------------------------------------------
__global__ __launch_bounds__(512, 2) void lstm_step(
    const unsigned short* __restrict__ X,      // [SS][NN][256] bf16
    const unsigned short* __restrict__ Wcat,   // [2][1024][512] bf16
    const float* __restrict__ bperm,           // [2][1024]
    unsigned short* __restrict__ hping,        // [2 ping][2 dir][NN][256] bf16
    float* __restrict__ cstate,                // [2 dir][NN][256] f32
    float* __restrict__ hsum,                  // [NN] f32
    int s) {
    const int b     = blockIdx.x;              // 0..255
    const int dir   = b & 1;
    const int nblk  = (b >> 3) & 3;            // 0..3 (256 gate cols each)
    const int mslab = (((b & 7) >> 1) << 3) | (b >> 5);   // 0..31
    const int m0    = mslab * 256;
    const int n0    = nblk * 256;

    const int t = dir ? (SS - 1 - s) : s;
    const unsigned short* Xt    = X + (size_t)t * NN * DD;
    const unsigned short* hprev = hping + ((size_t)((s & 1) * 2 + dir)) * NN * 256;
    unsigned short*       hnext = hping + ((size_t)((((s + 1) & 1) * 2) + dir)) * NN * 256;
    const unsigned short* W     = Wcat + (size_t)dir * RGATE * KKD;
    const float*          bp    = bperm + dir * RGATE;
    float*                cdir  = cstate + (size_t)dir * NN * 256;

    __shared__ __align__(16) char smem[65536];
    // A dbuf: [0,16K)+[16K,32K); B dbuf: [32K,48K)+[48K,64K)
    // epilogue scratch (34.8 KB) overlays [0, ...) after the K-loop.

    const int tid  = threadIdx.x;
    const int lane = tid & 63;
    const int w    = tid >> 6;        // 0..7
    const int wm   = w >> 1, wn = w & 1;
    const int quad = lane >> 4, l15 = lane & 15;
    const int jq   = lane & 3,  rl  = lane >> 2;

    // staging lane constants: lane covers LDS (row=base+(lane>>2), seg=lane&3)
    // which must hold global seg (lane&3) ^ ((row>>1)&3) = (lane&3)^((lane>>3)&3)
    const int srow  = lane >> 2;
    const int gsegl = (lane & 3) ^ ((lane >> 3) & 3);

    auto stage = [&](int r, int buf) {
        const int k0 = (r & 7) * 32;                       // col within X or h
        const unsigned short* Asrc = (r < 8) ? Xt : hprev;
        char* Ad = smem + buf * 16384;
        char* Bd = smem + 32768 + buf * 16384;
        #pragma unroll
        for (int i = 0; i < 2; ++i) {
            const int lr = w * 32 + i * 16 + srow;         // local row 0..255
            async_copy16(Asrc + (size_t)(m0 + lr) * DD + k0 + gsegl * 8,
                         (void*)(Ad + (w * 32 + i * 16) * 64));
            async_copy16(W + (size_t)(n0 + lr) * KKD + r * 32 + gsegl * 8,
                         (void*)(Bd + (w * 32 + i * 16) * 64));
        }
    };

    f32x4 acc[4][8];
    #pragma unroll
    for (int i = 0; i < 4; ++i)
        #pragma unroll
        for (int j = 0; j < 8; ++j) acc[i][j] = f32x4{0.f, 0.f, 0.f, 0.f};

    stage(0, 0);
    __syncthreads();

    const int sA = (quad ^ ((l15 >> 1) & 3)) * 16;   // frag-read seg byte offset

    for (int r = 0; r < 16; ++r) {
        if (r < 15) stage(r + 1, (r + 1) & 1);       // prefetch next tile
        const char* Ab = smem + (r & 1) * 16384;
        const char* Bb = smem + 32768 + (r & 1) * 16384;
        short8 af[4], bf[8];
        #pragma unroll
        for (int mt = 0; mt < 4; ++mt)
            af[mt] = *(const short8*)(Ab + (wm * 64 + mt * 16 + l15) * 64 + sA);
        #pragma unroll
        for (int nt = 0; nt < 8; ++nt)
            bf[nt] = *(const short8*)(Bb + (wn * 128 + nt * 16 + l15) * 64 + sA);
        #pragma unroll
        for (int mt = 0; mt < 4; ++mt)
            #pragma unroll
            for (int nt = 0; nt < 8; ++nt)
                acc[mt][nt] = __builtin_amdgcn_mfma_f32_16x16x32_bf16(
                    af[mt], bf[nt], acc[mt][nt], 0, 0, 0);
        __syncthreads();   // drains prefetch (vmcnt0) + all readers done w/ buf
    }

    // ---- epilogue: regroup gates (C/D -> unit-quads) via wave-private LDS ----
    float* my = (float*)smem + w * 1088;   // 16 x 68 floats per wave (34.8 KB)
    float hs[4] = {0.f, 0.f, 0.f, 0.f};

    #pragma unroll
    for (int half = 0; half < 2; ++half) {
        const int j0 = nblk * 64 + wn * 32 + half * 16 + jq * 4;  // global unit
        f32x4 bias4[4];
        #pragma unroll
        for (int jj = 0; jj < 4; ++jj)
            bias4[jj] = *(const f32x4*)(bp + 4 * (j0 + jj));
        #pragma unroll
        for (int mt = 0; mt < 4; ++mt) {
            #pragma unroll
            for (int nt = 0; nt < 4; ++nt) {
                const int ntg = half * 4 + nt;
                #pragma unroll
                for (int v = 0; v < 4; ++v)
                    my[(quad * 4 + v) * 68 + nt * 16 + l15] = acc[mt][ntg][v];
            }
            asm volatile("s_waitcnt lgkmcnt(0)" ::: "memory");
            const int mg = m0 + wm * 64 + mt * 16 + rl;
            float* cptr = cdir + (size_t)mg * 256 + j0;
            f32x4 cold = *(const f32x4*)cptr;
            f32x4 cnew;
            ushort4 hp;
            float lsum = 0.f;
            #pragma unroll
            for (int jj = 0; jj < 4; ++jj) {
                f32x4 g  = *(const f32x4*)(my + rl * 68 + (jq * 4 + jj) * 4);
                f32x4 bb = bias4[jj];
                const float gi = sigm(g.x + bb.x);   // i
                const float gf = sigm(g.y + bb.y);   // f
                const float gg = tanh_(g.z + bb.z);  // g
                const float go = sigm(g.w + bb.w);   // o
                const float cn = gf * cold[jj] + gi * gg;
                cnew[jj] = cn;
                const float hv = go * tanh_(cn);
                lsum += hv;
                ((unsigned short*)&hp)[jj] = f2bf(hv);
            }
            *(f32x4*)cptr = cnew;
            *(ushort4*)(hnext + (size_t)mg * 256 + j0) = hp;
            hs[mt] += lsum;
        }
    }

    // per-row partial sums -> one atomic per (wave, row)
    #pragma unroll
    for (int mt = 0; mt < 4; ++mt) {
        float v = hs[mt];
        v += __shfl_xor(v, 1);
        v += __shfl_xor(v, 2);
        if (jq == 0) atomicAdd(&hsum[m0 + wm * 64 + mt * 16 + rl], v);
    }
}

__global__ void bcast_out(const float* __restrict__ hsum, float* __restrict__ out) {
    const int n = blockIdx.x;
    const float v = hsum[n] * (1.0f / 512.0f);
    float2 p; p.x = v; p.y = v;
    ((float2*)(out + (size_t)n * 512))[threadIdx.x] = p;
}

extern "C" void kernel_launch(void* const* d_in, const int* in_sizes, int n_in,
                              void* d_out, int out_size, void* d_ws, size_t ws_size,
                              hipStream_t stream) {
    const float* emb  = (const float*)d_in[0];
    const float* wihf = (const float*)d_in[1];
    const float* whhf = (const float*)d_in[2];
    const float* bf   = (const float*)d_in[3];
    const float* wihb = (const float*)d_in[4];
    const float* whhb = (const float*)d_in[5];
    const float* bb   = (const float*)d_in[6];
    const int*   idx  = (const int*)d_in[7];
    float* out = (float*)d_out;

    // workspace layout (bytes)
    char* ws = (char*)d_ws;
    unsigned short* X     = (unsigned short*)(ws);               // 83,886,080  X[t][n][256] bf16
    unsigned short* Wcat  = (unsigned short*)(ws + 83886080);    //  2,097,152  [2][1024][512] bf16
    float*          bperm = (float*)(ws + 85983232);             //      8,192  [2][1024] f32
    unsigned short* hping = (unsigned short*)(ws + 85991424);    // 16,777,216  [2][2][8192][256] bf16
    float*          cst   = (float*)(ws + 102768640);            // 16,777,216  [2][8192][256] f32
    float*          hsum  = (float*)(ws + 119545856);            //     32,768  [8192] f32
    // total: 119,578,624 B

    hipMemsetAsync(hping, 0, 8388608, stream);                   // h ping0, both dirs
    hipMemsetAsync(cst, 0, 16777216 + 32768, stream);            // c + hsum (contiguous)

    convert_w<<<4096, 256, 0, stream>>>(wihf, whhf, bf, wihb, whhb, bb, Wcat, bperm);
    gather_x<<<2560, 256, 0, stream>>>(emb, idx, X);
    for (int s = 0; s < SS; ++s)
        lstm_step<<<256, 512, 0, stream>>>(X, Wcat, bperm, hping, cst, hsum, s);
    bcast_out<<<NN, 256, 0, stream>>>(hsum, out);
}